// Round 3
// baseline (235.431 us; speedup 1.0000x reference)
//
#include <hip/hip_runtime.h>

#define Kst 256
#define Dd 256
#define Vv 50000
#define VPAD 50176
#define Tt 512
#define Bb 256
#define KP1 257
#define MD 512
#define NROWS (KP1*KP1)   // 66049
#define EPSf 1e-5f

#define VB2 196           // vocab blocks (256 v each)
#define VB3 (VB2*4)       // per-wave lse partials per k row

typedef __attribute__((ext_vector_type(8))) short short8;
typedef __attribute__((ext_vector_type(4))) float f32x4;
typedef __attribute__((ext_vector_type(4))) unsigned u32x4;
typedef __attribute__((ext_vector_type(2))) unsigned u32x2;

__device__ __forceinline__ unsigned short f2bf(float f) {
    unsigned u = __builtin_bit_cast(unsigned, f);
    unsigned r = (u + 0x7fffu + ((u >> 16) & 1u)) >> 16;
    return (unsigned short)r;
}
__device__ __forceinline__ float bf2f(unsigned short u) {
    return __builtin_bit_cast(float, ((unsigned)u) << 16);
}
// truncating pack (MFMA inputs only)
__device__ __forceinline__ unsigned bfpack(float lo, float hi) {
    return __builtin_amdgcn_perm(__builtin_bit_cast(unsigned, hi),
                                 __builtin_bit_cast(unsigned, lo), 0x07060302u);
}
// rounding pack (stores feeding final outputs)
__device__ __forceinline__ unsigned f2bf2(float lo, float hi) {
    return (unsigned)f2bf(lo) | ((unsigned)f2bf(hi) << 16);
}

// ---------------- K_hP: MFMA preprocessing + dec_W fragment pack ----------------
// bid [0,8):      h = LN(...) -> h_bf
// bid [8,44):     P0/P1
// bid [44,108):   tdwg fragment layout, Gt, Bt
// bid [108,6380): dwP = bf16(dec_W) in MFMA-fragment layout:
//   value dec_W[v][k], v = vb*256+wvv*64+l15*4+ctv, k = ks*32+q*8+e
//   -> short8 at dwP[((((vb*8+ks)*16 + wvv*4+ctv)*64 + q*16+l15)*8]
__global__ __launch_bounds__(256) void k_hP(
    const float* __restrict__ lembs, const float* __restrict__ em_W,
    const float* __restrict__ em_bias, const float* __restrict__ em_g,
    const float* __restrict__ em_beta, unsigned short* __restrict__ h_bf,
    const float* __restrict__ tlembs, const float* __restrict__ tm_W,
    float* __restrict__ P0, float* __restrict__ P1,
    const float* __restrict__ td_W, const float* __restrict__ tn_g,
    const float* __restrict__ tn_beta, const float* __restrict__ td_b,
    unsigned short* __restrict__ tdwg_bf, float* __restrict__ Gt,
    float* __restrict__ Bt, const float* __restrict__ dec_W,
    unsigned short* __restrict__ dwP)
{
    int bid = blockIdx.x;
    int tid = threadIdx.x, lane = tid & 63, wv = tid >> 6;
    int l15 = lane & 15, q = lane >> 4;

    if (bid >= 108) {
        // ---- dec_W fragment pack: 8 rows per block, wave covers 2 rows ----
        int pb = bid - 108;                    // 0..6271
        int v = pb*8 + wv*2 + (lane >> 5);     // 0..50175
        int l32 = lane & 31;
        int vr = v < Vv ? v : Vv-1;
        const float* src = dec_W + (size_t)vr*Dd + l32*8;
        float4 f0 = *(const float4*)(src);
        float4 f1 = *(const float4*)(src + 4);
        u32x4 pk;
        pk.x = bfpack(f0.x, f0.y);
        pk.y = bfpack(f0.z, f0.w);
        pk.z = bfpack(f1.x, f1.y);
        pk.w = bfpack(f1.z, f1.w);
        int ks = l32 >> 2, q2 = l32 & 3;
        int vb2 = v >> 8, vl = v & 255;
        int wvv = vl >> 6, ctv = vl & 3, l15v = (vl >> 2) & 15;
        *(short8*)(dwP + ((((size_t)vb2*8 + ks)*16 + wvv*4 + ctv)*64
                          + (q2*16 + l15v))*8) = __builtin_bit_cast(short8, pk);
        return;
    }

    if (bid >= 44) {
        int c = (bid - 44)*4 + wv;
        const float4* w4 = (const float4*)(td_W + (size_t)c*MD);
        const float4* g4 = (const float4*)tn_g;
        const float4* b4 = (const float4*)tn_beta;
        float sg = 0.f, sb = 0.f;
        short8 o;
        #pragma unroll
        for (int u = 0; u < 2; ++u) {
            int j4 = lane*2 + u;
            float4 w = w4[j4], g = g4[j4], bt = b4[j4];
            sg += w.x*g.x + w.y*g.y + w.z*g.z + w.w*g.w;
            sb += w.x*bt.x + w.y*bt.y + w.z*bt.z + w.w*bt.w;
            o[u*4+0] = (short)f2bf(w.x*g.x);
            o[u*4+1] = (short)f2bf(w.y*g.y);
            o[u*4+2] = (short)f2bf(w.z*g.z);
            o[u*4+3] = (short)f2bf(w.w*g.w);
        }
        {
            int wvv = c >> 6, l15v = (c >> 2) & 15, ctv = c & 3;
            int ksv = lane >> 2, qv = lane & 3;
            *(short8*)(tdwg_bf +
                ((((size_t)wvv*16 + ksv)*4 + ctv)*64 + (qv*16 + l15v))*8) = o;
        }
        #pragma unroll
        for (int dd = 32; dd > 0; dd >>= 1) {
            sg += __shfl_xor(sg, dd);
            sb += __shfl_xor(sb, dd);
        }
        if (lane == 0) { Gt[c] = sg; Bt[c] = sb + td_b[c]; }
        return;
    }

    __shared__ short ta[32][264];
    __shared__ float lsep[4][32][2];
    __shared__ float musig[32][2];

    int job, r0, cb, koff, BK;
    const float* Arow; const float* Brow;
    if (bid < 8) {
        job = 0; r0 = bid*32; cb = 0; koff = 0; BK = Dd;
        Arow = lembs; Brow = em_W;
    } else {
        int b2 = bid - 8;
        int half = b2 / 18;
        int b3 = b2 % 18;
        job = 1 + half;
        r0 = (b3 >> 1) * 32;
        cb = (b3 & 1) * 256;
        koff = half * 256; BK = MD;
        Arow = tlembs; Brow = tm_W;
    }

    {
        int row = tid >> 3, seg = (tid & 7) * 32;
        int r = r0 + row;
        if (r > 256) r = 256;
        const float4* s4 = (const float4*)(Arow + (size_t)r*Dd + seg);
        #pragma unroll
        for (int u = 0; u < 4; ++u) {
            float4 f0 = s4[u*2], f1 = s4[u*2+1];
            u32x4 pk;
            pk.x = bfpack(f0.x, f0.y);
            pk.y = bfpack(f0.z, f0.w);
            pk.z = bfpack(f1.x, f1.y);
            pk.w = bfpack(f1.z, f1.w);
            *(short8*)&ta[row][seg + u*8] = __builtin_bit_cast(short8, pk);
        }
    }
    __syncthreads();

    const float* bptr[4];
    #pragma unroll
    for (int ct = 0; ct < 4; ++ct) {
        int j = cb + wv*64 + ct*16 + l15;
        bptr[ct] = Brow + (size_t)j*BK + koff + q*8;
    }
    f32x4 acc[2][4];
    #pragma unroll
    for (int rt = 0; rt < 2; ++rt)
        #pragma unroll
        for (int ct = 0; ct < 4; ++ct)
            acc[rt][ct] = (f32x4){0.f,0.f,0.f,0.f};
    for (int ks = 0; ks < 8; ++ks) {
        short8 a0 = *(const short8*)&ta[ 0 + l15][ks*32 + q*8];
        short8 a1 = *(const short8*)&ta[16 + l15][ks*32 + q*8];
        short8 b[4];
        #pragma unroll
        for (int ct = 0; ct < 4; ++ct) {
            float4 f0 = *(const float4*)(bptr[ct] + ks*32);
            float4 f1 = *(const float4*)(bptr[ct] + ks*32 + 4);
            u32x4 pk;
            pk.x = bfpack(f0.x, f0.y);
            pk.y = bfpack(f0.z, f0.w);
            pk.z = bfpack(f1.x, f1.y);
            pk.w = bfpack(f1.z, f1.w);
            b[ct] = __builtin_bit_cast(short8, pk);
        }
        #pragma unroll
        for (int ct = 0; ct < 4; ++ct) {
            acc[0][ct] = __builtin_amdgcn_mfma_f32_16x16x32_bf16(a0, b[ct], acc[0][ct], 0,0,0);
            acc[1][ct] = __builtin_amdgcn_mfma_f32_16x16x32_bf16(a1, b[ct], acc[1][ct], 0,0,0);
        }
    }

    if (job != 0) {
        float* Pd = (job == 1) ? P0 : P1;
        #pragma unroll
        for (int rt = 0; rt < 2; ++rt) {
            #pragma unroll
            for (int reg = 0; reg < 4; ++reg) {
                int r = r0 + rt*16 + q*4 + reg;
                if (r < KP1) {
                    float* dst = Pd + (size_t)r*MD + cb + wv*64;
                    #pragma unroll
                    for (int ct = 0; ct < 4; ++ct)
                        dst[ct*16 + l15] = acc[rt][ct][reg];
                }
            }
        }
        return;
    }

    float bias_c[4];
    #pragma unroll
    for (int ct = 0; ct < 4; ++ct)
        bias_c[ct] = em_bias[wv*64 + ct*16 + l15];
    #pragma unroll
    for (int rt = 0; rt < 2; ++rt) {
        #pragma unroll
        for (int reg = 0; reg < 4; ++reg) {
            int r = r0 + rt*16 + q*4 + reg;
            #pragma unroll
            for (int ct = 0; ct < 4; ++ct) {
                float lv = lembs[(size_t)r*Dd + wv*64 + ct*16 + l15];
                acc[rt][ct][reg] = lv + fmaxf(acc[rt][ct][reg] + bias_c[ct], 0.f);
            }
        }
    }
    #pragma unroll
    for (int rt = 0; rt < 2; ++rt) {
        #pragma unroll
        for (int reg = 0; reg < 4; ++reg) {
            float s  = ((acc[rt][0][reg] + acc[rt][1][reg]) + (acc[rt][2][reg] + acc[rt][3][reg]));
            float ss = ((acc[rt][0][reg]*acc[rt][0][reg] + acc[rt][1][reg]*acc[rt][1][reg])
                      + (acc[rt][2][reg]*acc[rt][2][reg] + acc[rt][3][reg]*acc[rt][3][reg]));
            s  += __shfl_xor(s, 1);  ss += __shfl_xor(ss, 1);
            s  += __shfl_xor(s, 2);  ss += __shfl_xor(ss, 2);
            s  += __shfl_xor(s, 4);  ss += __shfl_xor(ss, 4);
            s  += __shfl_xor(s, 8);  ss += __shfl_xor(ss, 8);
            if (l15 == 0) {
                int rw = rt*16 + q*4 + reg;
                lsep[wv][rw][0] = s;
                lsep[wv][rw][1] = ss;
            }
        }
    }
    __syncthreads();
    if (tid < 32) {
        float s  = (lsep[0][tid][0] + lsep[1][tid][0]) + (lsep[2][tid][0] + lsep[3][tid][0]);
        float ss = (lsep[0][tid][1] + lsep[1][tid][1]) + (lsep[2][tid][1] + lsep[3][tid][1]);
        float mu = s * (1.f/Dd);
        musig[tid][0] = mu;
        musig[tid][1] = rsqrtf(ss*(1.f/Dd) - mu*mu + EPSf);
    }
    __syncthreads();
    float gl[4], bl[4];
    #pragma unroll
    for (int ct = 0; ct < 4; ++ct) {
        gl[ct] = em_g[wv*64 + ct*16 + l15];
        bl[ct] = em_beta[wv*64 + ct*16 + l15];
    }
    #pragma unroll
    for (int rt = 0; rt < 2; ++rt) {
        #pragma unroll
        for (int reg = 0; reg < 4; ++reg) {
            int rw = rt*16 + q*4 + reg;
            int r = r0 + rw;
            float mu = musig[rw][0], rs = musig[rw][1];
            unsigned short* dst = h_bf + (size_t)r*Dd + wv*64;
            #pragma unroll
            for (int ct = 0; ct < 4; ++ct)
                dst[ct*16 + l15] = f2bf((acc[rt][ct][reg] - mu)*rs*gl[ct] + bl[ct]);
        }
    }
}

// ---------------- K_em v7: fragment-layout B (contiguous, no LDS-B, no in-loop barriers) ----------------
__global__ __launch_bounds__(256) void k_em_mfma7(
    const unsigned short* __restrict__ dwP, const float* __restrict__ dec_b,
    const unsigned short* __restrict__ h_bf, float* __restrict__ part,
    unsigned short* __restrict__ E2)
{
    int kg = blockIdx.x, vb = blockIdx.y;   // kg fastest: adjacent blocks share dwP slice
    int tid = threadIdx.x, lane = tid & 63, wv = tid >> 6;
    int l15 = lane & 15, q = lane >> 4;
    __shared__ short hs[64][264];           // A tile (33.8 KB)

    {
        int row = tid >> 2, c0 = (tid & 3) * 64;
        const short8* src = (const short8*)(h_bf + (size_t)(kg*64 + row)*Dd + c0);
        #pragma unroll
        for (int u = 0; u < 8; ++u)
            *(short8*)&hs[row][c0 + u*8] = src[u];
    }
    __syncthreads();

    f32x4 acc[4][4];
    #pragma unroll
    for (int mt = 0; mt < 4; ++mt)
        #pragma unroll
        for (int ct = 0; ct < 4; ++ct)
            acc[mt][ct] = (f32x4){0.f,0.f,0.f,0.f};

    // B fragments: frag(ks, ct) at bb8[(ks*16 + ct)*64 + lane], depth-3 circular prefetch
    const short8* bb8 = (const short8*)dwP + ((size_t)vb*8*16 + wv*4)*64 + lane;
    short8 Bf[3][4];
    #define LDB_EM(slot, kk) { \
        Bf[slot][0] = bb8[((kk)*16 + 0)*64]; \
        Bf[slot][1] = bb8[((kk)*16 + 1)*64]; \
        Bf[slot][2] = bb8[((kk)*16 + 2)*64]; \
        Bf[slot][3] = bb8[((kk)*16 + 3)*64]; }
    LDB_EM(0, 0)
    LDB_EM(1, 1)
    #pragma unroll
    for (int ks = 0; ks < 8; ++ks) {
        if (ks < 6) LDB_EM((ks+2)%3, ks+2)
        short8 a[4];
        #pragma unroll
        for (int mt = 0; mt < 4; ++mt)
            a[mt] = *(const short8*)&hs[mt*16 + l15][ks*32 + q*8];
        #pragma unroll
        for (int mt = 0; mt < 4; ++mt)
            #pragma unroll
            for (int ct = 0; ct < 4; ++ct)
                acc[mt][ct] = __builtin_amdgcn_mfma_f32_16x16x32_bf16(a[mt], Bf[ks%3][ct], acc[mt][ct], 0,0,0);
    }
    #undef LDB_EM

    int vcol[4]; bool vok[4];
    #pragma unroll
    for (int ct = 0; ct < 4; ++ct) {
        int v = vb*256 + wv*64 + l15*4 + ct;
        vok[ct] = (v < Vv);
        vcol[ct] = v < Vv ? v : Vv-1;
    }
    #pragma unroll
    for (int ct = 0; ct < 4; ++ct) {
        if (vok[ct]) {
            float db = dec_b[vcol[ct]];
            #pragma unroll
            for (int mt = 0; mt < 4; ++mt)
                #pragma unroll
                for (int reg = 0; reg < 4; ++reg)
                    acc[mt][ct][reg] += db;
        } else {
            #pragma unroll
            for (int mt = 0; mt < 4; ++mt)
                #pragma unroll
                for (int reg = 0; reg < 4; ++reg)
                    acc[mt][ct][reg] = -1e30f;
        }
    }
    #pragma unroll
    for (int mt = 0; mt < 4; ++mt) {
        #pragma unroll
        for (int reg = 0; reg < 4; ++reg) {
            int k = kg*64 + mt*16 + q*4 + reg;
            u32x2 p;
            p.x = f2bf2(acc[mt][0][reg], acc[mt][1][reg]);
            p.y = f2bf2(acc[mt][2][reg], acc[mt][3][reg]);
            *(u32x2*)(E2 + (size_t)k*VPAD + vb*256 + wv*64 + l15*4) = p;
        }
    }
    #pragma unroll
    for (int mt = 0; mt < 4; ++mt) {
        #pragma unroll
        for (int reg = 0; reg < 4; ++reg) {
            float m = fmaxf(fmaxf(acc[mt][0][reg], acc[mt][1][reg]),
                            fmaxf(acc[mt][2][reg], acc[mt][3][reg]));
            m = fmaxf(m, __shfl_xor(m, 1));
            m = fmaxf(m, __shfl_xor(m, 2));
            m = fmaxf(m, __shfl_xor(m, 4));
            m = fmaxf(m, __shfl_xor(m, 8));
            float s = __expf(acc[mt][0][reg] - m) + __expf(acc[mt][1][reg] - m)
                    + __expf(acc[mt][2][reg] - m) + __expf(acc[mt][3][reg] - m);
            s += __shfl_xor(s, 1);
            s += __shfl_xor(s, 2);
            s += __shfl_xor(s, 4);
            s += __shfl_xor(s, 8);
            if (l15 == 0) {
                int k = kg*64 + mt*16 + q*4 + reg;
                part[((size_t)k*VB3 + vb*4 + wv)*2]     = m;
                part[((size_t)k*VB3 + vb*4 + wv)*2 + 1] = s;
            }
        }
    }
}

// ---------------- K_comb: combine partials -> lse_em[k] (unchanged) ----------------
__global__ __launch_bounds__(64) void k_em_comb3(
    const float* __restrict__ part, float* __restrict__ lse_em)
{
    int k = blockIdx.x, lane = threadIdx.x;
    float m = -1e30f, s = 0.f;
    for (int vb = lane; vb < VB3; vb += 64) {
        float m2 = part[((size_t)k*VB3+vb)*2], s2 = part[((size_t)k*VB3+vb)*2+1];
        if (m2 > m) { s = s*__expf(m - m2) + s2; m = m2; }
        else          s += s2*__expf(m2 - m);
    }
    #pragma unroll
    for (int d = 1; d < 64; d <<= 1) {
        float mo = __shfl_xor(m, d), so = __shfl_xor(s, d);
        float mn = fmaxf(m, mo);
        s = s*__expf(m - mn) + so*__expf(mo - mn);
        m = mn;
    }
    if (lane == 0) lse_em[k] = m + logf(s);
}

// ---------------- K_trans11: depth-3 B prefetch + pipelined staging ----------------
__global__ __launch_bounds__(256, 4) void k_trans11(
    const float* __restrict__ tlembs, const float* __restrict__ P0,
    const float* __restrict__ P1, const float* __restrict__ tm_bias,
    const short* __restrict__ tdwg_bf, const float* __restrict__ Gt,
    const float* __restrict__ Bt, float* __restrict__ lse_t,
    unsigned short* __restrict__ Td)
{
    __shared__ short th[32][520];
    __shared__ float musig[32][2];
    __shared__ float lsep[4][32][2];
    int tid = threadIdx.x, lane = tid & 63, wv = tid >> 6;
    int l15 = lane & 15, q = lane >> 4;
    int r0 = blockIdx.x * 32;

    // ---- stage + LN stats fused; 1-deep load pipeline ----
    {
        const float4* bias0 = (const float4*)tm_bias;
        const float4* bias1 = (const float4*)(tm_bias + 256);
        float4 c0 = bias0[lane], c1 = bias1[lane];
        int i0a[8], i1a[8];
        #pragma unroll
        for (int i = 0; i < 8; ++i) {
            int r = r0 + wv*8 + i; if (r >= NROWS) r = NROWS - 1;
            i0a[i] = r / KP1; i1a[i] = r - i0a[i]*KP1;
        }
        float4 a0 = ((const float4*)(P0 + (size_t)i0a[0]*MD))[lane];
        float4 b0 = ((const float4*)(P1 + (size_t)i1a[0]*MD))[lane];
        float4 t0 = ((const float4*)(tlembs + (size_t)i0a[0]*Dd))[lane];
        float4 a1 = ((const float4*)(P0 + (size_t)i0a[0]*MD + 256))[lane];
        float4 b1 = ((const float4*)(P1 + (size_t)i1a[0]*MD + 256))[lane];
        float4 t1 = ((const float4*)(tlembs + (size_t)i1a[0]*Dd))[lane];
        #pragma unroll
        for (int i = 0; i < 8; ++i) {
            float4 na0, nb0, nt0, na1, nb1, nt1;
            if (i < 7) {
                na0 = ((const float4*)(P0 + (size_t)i0a[i+1]*MD))[lane];
                nb0 = ((const float4*)(P1 + (size_t)i1a[i+1]*MD))[lane];
                nt0 = ((const float4*)(tlembs + (size_t)i0a[i+1]*Dd))[lane];
                na1 = ((const float4*)(P0 + (size_t)i0a[i+1]*MD + 256))[lane];
                nb1 = ((const float4*)(P1 + (size_t)i1a[i+1]*MD + 256))[lane];
                nt1 = ((const float4*)(tlembs + (size_t)i1a[i+1]*Dd))[lane];
            }
            int row = wv*8 + i;
            float v0 = t0.x + fmaxf(a0.x+b0.x+c0.x, 0.f);
            float v1 = t0.y + fmaxf(a0.y+b0.y+c0.y, 0.f);
            float v2 = t0.z + fmaxf(a0.z+b0.z+c0.z, 0.f);
            float v3 = t0.w + fmaxf(a0.w+b0.w+c0.w, 0.f);
            float v4 = t1.x + fmaxf(a1.x+b1.x+c1.x, 0.f);
            float v5 = t1.y + fmaxf(a1.y+b1.y+c1.y, 0.f);
            float v6 = t1.z + fmaxf(a1.z+b1.z+c1.z, 0.f);
            float v7 = t1.w + fmaxf(a1.w+b1.w+c1.w, 0.f);
            u32x2 p0; p0.x = bfpack(v0, v1); p0.y = bfpack(v2, v3);
            u32x2 p1; p1.x = bfpack(v4, v5); p1.y = bfpack(v6, v7);
            *(u32x2*)&th[row][lane*4]       = p0;
            *(u32x2*)&th[row][256 + lane*4] = p1;
            float s  = ((v0+v1)+(v2+v3)) + ((v4+v5)+(v6+v7));
            float ss = ((v0*v0+v1*v1)+(v2*v2+v3*v3)) + ((v4*v4+v5*v5)+(v6*v6+v7*v7));
            #pragma unroll
            for (int d = 1; d < 64; d <<= 1) {
                s  += __shfl_xor(s, d);
                ss += __shfl_xor(ss, d);
            }
            if (lane == 0) {
                float mu = s * (1.f/MD);
                musig[row][0] = mu;
                musig[row][1] = rsqrtf(ss*(1.f/MD) - mu*mu + EPSf);
            }
            a0 = na0; b0 = nb0; t0 = nt0; a1 = na1; b1 = nb1; t1 = nt1;
        }
    }
    __syncthreads();

    // ---- MFMA; fragment-layout B, depth-3 circular prefetch ----
    f32x4 acc[2][4];
    #pragma unroll
    for (int rt = 0; rt < 2; ++rt)
        #pragma unroll
        for (int ct = 0; ct < 4; ++ct)
            acc[rt][ct] = (f32x4){0.f, 0.f, 0.f, 0.f};
    const short* bb = tdwg_bf + (size_t)wv*32768 + (size_t)lane*8;  // wv*16*4*64*8
    short8 Bf[3][4];
    #define LDB_TR(slot, kk) { const short* nxt = bb + (size_t)(kk)*2048; \
        Bf[slot][0] = *(const short8*)(nxt); \
        Bf[slot][1] = *(const short8*)(nxt + 512); \
        Bf[slot][2] = *(const short8*)(nxt + 1024); \
        Bf[slot][3] = *(const short8*)(nxt + 1536); }
    LDB_TR(0, 0)
    LDB_TR(1, 1)
    #pragma unroll
    for (int ks = 0; ks < 16; ++ks) {
        if (ks < 14) LDB_TR((ks+2)%3, ks+2)
        int ko = ks*32 + q*8;
        short8 a0 = *(const short8*)&th[ 0 + l15][ko];
        short8 a1 = *(const short8*)&th[16 + l15][ko];
        acc[0][0] = __builtin_amdgcn_mfma_f32_16x16x32_bf16(a0, Bf[ks%3][0], acc[0][0], 0,0,0);
        acc[1][0] = __builtin_amdgcn_mfma_f32_16x16x32_bf16(a1, Bf[ks%3][0], acc[1][0], 0,0,0);
        acc[0][1] = __builtin_amdgcn_mfma_f32_16x16x32_bf16(a0, Bf[ks%3][1], acc[0][1], 0,0,0);
        acc[1][1] = __builtin_amdgcn_mfma_f32_16x16x32_bf16(a1, Bf[ks%3][1], acc[1][1], 0,0,0);
        acc[0][2] = __builtin_amdgcn_mfma_f32_16x16x32_bf16(a0, Bf[ks%3][2], acc[0][2], 0,0,0);
        acc[1][2] = __builtin_amdgcn_mfma_f32_16x16x32_bf16(a1, Bf[ks%3][2], acc[1][2], 0,0,0);
        acc[0][3] = __builtin_amdgcn_mfma_f32_16x16x32_bf16(a0, Bf[ks%3][3], acc[0][3], 0,0,0);
        acc[1][3] = __builtin_amdgcn_mfma_f32_16x16x32_bf16(a1, Bf[ks%3][3], acc[1][3], 0,0,0);
    }
    #undef LDB_TR

    // ---- LN apply + packed contiguous Td stores + softmax partials ----
    float4 Gc = *(const float4*)(Gt + wv*64 + l15*4);
    float4 Bc = *(const float4*)(Bt + wv*64 + l15*4);
    #pragma unroll
    for (int rt = 0; rt < 2; ++rt) {
        #pragma unroll
        for (int reg = 0; reg < 4; ++reg) {
            int rw = rt*16 + q*4 + reg;
            float mu = musig[rw][0], rs = musig[rw][1];
            float e0 = rs*(acc[rt][0][reg] - mu*Gc.x) + Bc.x;
            float e1 = rs*(acc[rt][1][reg] - mu*Gc.y) + Bc.y;
            float e2 = rs*(acc[rt][2][reg] - mu*Gc.z) + Bc.z;
            float e3 = rs*(acc[rt][3][reg] - mu*Gc.w) + Bc.w;
            long r = (long)r0 + rw;
            if (r < NROWS) {
                u32x2 p;
                p.x = f2bf2(e0, e1);
                p.y = f2bf2(e2, e3);
                *(u32x2*)(Td + (size_t)r*Kst + wv*64 + l15*4) = p;
            }
            float m = fmaxf(fmaxf(e0, e1), fmaxf(e2, e3));
            m = fmaxf(m, __shfl_xor(m, 1));
            m = fmaxf(m, __shfl_xor(m, 2));
            m = fmaxf(m, __shfl_xor(m, 4));
            m = fmaxf(m, __shfl_xor(m, 8));
            float s = __expf(e0 - m) + __expf(e1 - m) + __expf(e2 - m) + __expf(e3 - m);
            s += __shfl_xor(s, 1);
            s += __shfl_xor(s, 2);
            s += __shfl_xor(s, 4);
            s += __shfl_xor(s, 8);
            if (l15 == 0) {
                lsep[wv][rw][0] = m;
                lsep[wv][rw][1] = s;
            }
        }
    }
    __syncthreads();
    if (tid < 32) {
        int r = r0 + tid;
        if (r < NROWS) {
            float m0 = lsep[0][tid][0], m1 = lsep[1][tid][0];
            float m2 = lsep[2][tid][0], m3 = lsep[3][tid][0];
            float mg = fmaxf(fmaxf(m0, m1), fmaxf(m2, m3));
            float s = lsep[0][tid][1]*__expf(m0-mg) + lsep[1][tid][1]*__expf(m1-mg)
                    + lsep[2][tid][1]*__expf(m2-mg) + lsep[3][tid][1]*__expf(m3-mg);
            lse_t[r] = mg + logf(s);
        }
    }
}

// ---------------- K_gather: 2 timesteps per thread, 1 atomic ----------------
#define GT_CH 2
__global__ __launch_bounds__(256) void k_gather3(
    const int* __restrict__ x, const int* __restrict__ z,
    const unsigned short* __restrict__ E2, const float* __restrict__ lse_em,
    const unsigned short* __restrict__ Td, const float* __restrict__ lse_t,
    float* __restrict__ out)
{
    int b = threadIdx.x;
    int t0 = blockIdx.x * GT_CH;
    float accv = 0.f;
    #pragma unroll
    for (int u = 0; u < GT_CH; ++u) {
        int t = t0 + u;
        int zc = z[t*Bb + b];
        int xv = x[t*Bb + b];
        int i0 = (t >= 2) ? z[(t-2)*Bb + b] : Kst;
        int i1 = (t >= 1) ? z[(t-1)*Bb + b] : Kst;
        int lin = i0*KP1 + i1;
        accv += bf2f(E2[(size_t)zc*VPAD + xv]) - lse_em[zc]
              + bf2f(Td[(size_t)lin*Kst + zc]) - lse_t[lin];
    }
    atomicAdd(&out[b], accv);
}

extern "C" void kernel_launch(void* const* d_in, const int* in_sizes, int n_in,
                              void* d_out, int out_size, void* d_ws, size_t ws_size,
                              hipStream_t stream)
{
    const int*   x       = (const int*)  d_in[0];
    const int*   z       = (const int*)  d_in[1];
    const float* lembs   = (const float*)d_in[2];
    const float* tlembs  = (const float*)d_in[3];
    const float* dec_W   = (const float*)d_in[4];
    const float* dec_b   = (const float*)d_in[5];
    const float* em_W    = (const float*)d_in[6];
    const float* em_bias = (const float*)d_in[7];
    const float* em_g    = (const float*)d_in[8];
    const float* em_beta = (const float*)d_in[9];
    const float* td_W    = (const float*)d_in[10];
    const float* td_b    = (const float*)d_in[11];
    const float* tm_W    = (const float*)d_in[12];
    const float* tm_bias = (const float*)d_in[13];
    const float* tn_g    = (const float*)d_in[14];
    const float* tn_beta = (const float*)d_in[15];
    float* out = (float*)d_out;

    float* ws     = (float*)d_ws;
    float* P0     = ws;                    // 131584
    float* P1     = P0 + 131584;           // 131584
    float* lse_em = P1 + 131584;           // 256
    float* part   = lse_em + 256;          // 256*784*2 = 401408
    float* lse_t  = part + 401408;         // 66052
    float* Gt     = lse_t + 66052;         // 256
    float* Bt     = Gt + 256;              // 256
    unsigned short* tdwg_bf = (unsigned short*)(Bt + 256);      // 131072 ushort (fragment layout)
    unsigned short* h_bf   = tdwg_bf + 131072;                  // 65536 ushort
    unsigned short* E2     = h_bf + 65536;                      // 256*50176 ushort (25.7MB)
    unsigned short* Td     = E2 + (size_t)Kst*VPAD;             // 66049*256 ushort (33.8MB)
    unsigned short* dwP    = Td + (size_t)NROWS*Kst;            // 50176*256 ushort (25.7MB)

    hipMemsetAsync(out, 0, Bb*sizeof(float), stream);
    k_hP<<<108 + VPAD/8, 256, 0, stream>>>(lembs, em_W, em_bias, em_g, em_beta, h_bf,
                                           tlembs, tm_W, P0, P1,
                                           td_W, tn_g, tn_beta, td_b, tdwg_bf, Gt, Bt,
                                           dec_W, dwP);
    k_em_mfma7<<<dim3(4, VB2), 256, 0, stream>>>(dwP, dec_b, h_bf, part, E2);
    k_em_comb3<<<Kst, 64, 0, stream>>>(part, lse_em);
    k_trans11<<<(NROWS + 31)/32, 256, 0, stream>>>(tlembs, P0, P1, tm_bias,
                                                   (const short*)tdwg_bf, Gt, Bt,
                                                   lse_t, Td);
    k_gather3<<<Tt/GT_CH, 256, 0, stream>>>(x, z, E2, lse_em, Td, lse_t, out);
}

// Round 4
// 204.360 us; speedup vs baseline: 1.1520x; 1.1520x over previous
//
#include <hip/hip_runtime.h>

#define Kst 256
#define Dd 256
#define Vv 50000
#define VPAD 50176
#define Tt 512
#define Bb 256
#define KP1 257
#define MD 512
#define NROWS (KP1*KP1)   // 66049
#define EPSf 1e-5f

#define VB2 196           // vocab blocks (256 v each)
#define VB3 (VB2*4)       // per-wave lse partials per k row
#define EMB 800           // em block ids [0,800) after xcd remap (25 grp * 4 kg * 8 xcd)

typedef __attribute__((ext_vector_type(8))) short short8;
typedef __attribute__((ext_vector_type(4))) float f32x4;
typedef __attribute__((ext_vector_type(4))) unsigned u32x4;
typedef __attribute__((ext_vector_type(2))) unsigned u32x2;

__device__ __forceinline__ unsigned short f2bf(float f) {
    unsigned u = __builtin_bit_cast(unsigned, f);
    unsigned r = (u + 0x7fffu + ((u >> 16) & 1u)) >> 16;
    return (unsigned short)r;
}
__device__ __forceinline__ float bf2f(unsigned short u) {
    return __builtin_bit_cast(float, ((unsigned)u) << 16);
}
// truncating pack (MFMA inputs only)
__device__ __forceinline__ unsigned bfpack(float lo, float hi) {
    return __builtin_amdgcn_perm(__builtin_bit_cast(unsigned, hi),
                                 __builtin_bit_cast(unsigned, lo), 0x07060302u);
}
// rounding pack (stores feeding final outputs)
__device__ __forceinline__ unsigned f2bf2(float lo, float hi) {
    return (unsigned)f2bf(lo) | ((unsigned)f2bf(hi) << 16);
}

// ---------------- K_hP: preprocessing ----------------
// bid [0,8):     h = LN(...) -> h_bf
// bid [8,44):    P0/P1
// bid [44,108):  tdwg fragment layout, Gt, Bt
// bid [108,500): dwP pack, gather-on-read / coalesced-write (392 blocks, half-slice each)
__global__ __launch_bounds__(256) void k_hP(
    const float* __restrict__ lembs, const float* __restrict__ em_W,
    const float* __restrict__ em_bias, const float* __restrict__ em_g,
    const float* __restrict__ em_beta, unsigned short* __restrict__ h_bf,
    const float* __restrict__ tlembs, const float* __restrict__ tm_W,
    float* __restrict__ P0, float* __restrict__ P1,
    const float* __restrict__ td_W, const float* __restrict__ tn_g,
    const float* __restrict__ tn_beta, const float* __restrict__ td_b,
    unsigned short* __restrict__ tdwg_bf, float* __restrict__ Gt,
    float* __restrict__ Bt, const float* __restrict__ dec_W,
    unsigned short* __restrict__ dwP)
{
    int bid = blockIdx.x;
    int tid = threadIdx.x, lane = tid & 63, wv = tid >> 6;
    int l15 = lane & 15, q = lane >> 4;

    if (bid >= 108) {
        // ---- dwP pack: slice-local entry E in [0,8192), short8 at dwP8[vb2*8192+E]
        // E = ks*1024 + fi*64 + le ; value = dec_W[vb2*256 + v][ks*32+q2*8 .. +8]
        //   v = (fi>>2)*64 + (le&15)*4 + (fi&3), q2 = le>>4
        int pb = bid - 108;               // 0..391
        int vb2 = pb >> 1, sub = pb & 1;
        #pragma unroll 2
        for (int j = 0; j < 8; ++j) {
            int E0 = sub*4096 + wv*1024 + j*128 + lane*2;
            #pragma unroll
            for (int b = 0; b < 2; ++b) {
                int E = E0 + b;
                int ks = E >> 10, fi = (E >> 6) & 15, le = E & 63;
                int q2 = le >> 4, lv = le & 15;
                int v = ((fi >> 2) << 6) + lv*4 + (fi & 3);
                int row = vb2*256 + v;
                if (row > Vv-1) row = Vv-1;
                const float* src = dec_W + (size_t)row*Dd + ks*32 + q2*8;
                float4 f0 = *(const float4*)(src);
                float4 f1 = *(const float4*)(src + 4);
                u32x4 pk;
                pk.x = bfpack(f0.x, f0.y);
                pk.y = bfpack(f0.z, f0.w);
                pk.z = bfpack(f1.x, f1.y);
                pk.w = bfpack(f1.z, f1.w);
                *(short8*)(dwP + ((size_t)vb2*8192 + E)*8) = __builtin_bit_cast(short8, pk);
            }
        }
        return;
    }

    if (bid >= 44) {
        int c = (bid - 44)*4 + wv;
        const float4* w4 = (const float4*)(td_W + (size_t)c*MD);
        const float4* g4 = (const float4*)tn_g;
        const float4* b4 = (const float4*)tn_beta;
        float sg = 0.f, sb = 0.f;
        short8 o;
        #pragma unroll
        for (int u = 0; u < 2; ++u) {
            int j4 = lane*2 + u;
            float4 w = w4[j4], g = g4[j4], bt = b4[j4];
            sg += w.x*g.x + w.y*g.y + w.z*g.z + w.w*g.w;
            sb += w.x*bt.x + w.y*bt.y + w.z*bt.z + w.w*bt.w;
            o[u*4+0] = (short)f2bf(w.x*g.x);
            o[u*4+1] = (short)f2bf(w.y*g.y);
            o[u*4+2] = (short)f2bf(w.z*g.z);
            o[u*4+3] = (short)f2bf(w.w*g.w);
        }
        {
            int wvv = c >> 6, l15v = (c >> 2) & 15, ctv = c & 3;
            int ksv = lane >> 2, qv = lane & 3;
            *(short8*)(tdwg_bf +
                ((((size_t)wvv*16 + ksv)*4 + ctv)*64 + (qv*16 + l15v))*8) = o;
        }
        #pragma unroll
        for (int dd = 32; dd > 0; dd >>= 1) {
            sg += __shfl_xor(sg, dd);
            sb += __shfl_xor(sb, dd);
        }
        if (lane == 0) { Gt[c] = sg; Bt[c] = sb + td_b[c]; }
        return;
    }

    __shared__ short ta[32][264];
    __shared__ float lsep[4][32][2];
    __shared__ float musig[32][2];

    int job, r0, cb, koff, BK;
    const float* Arow; const float* Brow;
    if (bid < 8) {
        job = 0; r0 = bid*32; cb = 0; koff = 0; BK = Dd;
        Arow = lembs; Brow = em_W;
    } else {
        int b2 = bid - 8;
        int half = b2 / 18;
        int b3 = b2 % 18;
        job = 1 + half;
        r0 = (b3 >> 1) * 32;
        cb = (b3 & 1) * 256;
        koff = half * 256; BK = MD;
        Arow = tlembs; Brow = tm_W;
    }

    {
        int row = tid >> 3, seg = (tid & 7) * 32;
        int r = r0 + row;
        if (r > 256) r = 256;
        const float4* s4 = (const float4*)(Arow + (size_t)r*Dd + seg);
        #pragma unroll
        for (int u = 0; u < 4; ++u) {
            float4 f0 = s4[u*2], f1 = s4[u*2+1];
            u32x4 pk;
            pk.x = bfpack(f0.x, f0.y);
            pk.y = bfpack(f0.z, f0.w);
            pk.z = bfpack(f1.x, f1.y);
            pk.w = bfpack(f1.z, f1.w);
            *(short8*)&ta[row][seg + u*8] = __builtin_bit_cast(short8, pk);
        }
    }
    __syncthreads();

    const float* bptr[4];
    #pragma unroll
    for (int ct = 0; ct < 4; ++ct) {
        int j = cb + wv*64 + ct*16 + l15;
        bptr[ct] = Brow + (size_t)j*BK + koff + q*8;
    }
    f32x4 acc[2][4];
    #pragma unroll
    for (int rt = 0; rt < 2; ++rt)
        #pragma unroll
        for (int ct = 0; ct < 4; ++ct)
            acc[rt][ct] = (f32x4){0.f,0.f,0.f,0.f};
    for (int ks = 0; ks < 8; ++ks) {
        short8 a0 = *(const short8*)&ta[ 0 + l15][ks*32 + q*8];
        short8 a1 = *(const short8*)&ta[16 + l15][ks*32 + q*8];
        short8 b[4];
        #pragma unroll
        for (int ct = 0; ct < 4; ++ct) {
            float4 f0 = *(const float4*)(bptr[ct] + ks*32);
            float4 f1 = *(const float4*)(bptr[ct] + ks*32 + 4);
            u32x4 pk;
            pk.x = bfpack(f0.x, f0.y);
            pk.y = bfpack(f0.z, f0.w);
            pk.z = bfpack(f1.x, f1.y);
            pk.w = bfpack(f1.z, f1.w);
            b[ct] = __builtin_bit_cast(short8, pk);
        }
        #pragma unroll
        for (int ct = 0; ct < 4; ++ct) {
            acc[0][ct] = __builtin_amdgcn_mfma_f32_16x16x32_bf16(a0, b[ct], acc[0][ct], 0,0,0);
            acc[1][ct] = __builtin_amdgcn_mfma_f32_16x16x32_bf16(a1, b[ct], acc[1][ct], 0,0,0);
        }
    }

    if (job != 0) {
        float* Pd = (job == 1) ? P0 : P1;
        #pragma unroll
        for (int rt = 0; rt < 2; ++rt) {
            #pragma unroll
            for (int reg = 0; reg < 4; ++reg) {
                int r = r0 + rt*16 + q*4 + reg;
                if (r < KP1) {
                    float* dst = Pd + (size_t)r*MD + cb + wv*64;
                    #pragma unroll
                    for (int ct = 0; ct < 4; ++ct)
                        dst[ct*16 + l15] = acc[rt][ct][reg];
                }
            }
        }
        return;
    }

    float bias_c[4];
    #pragma unroll
    for (int ct = 0; ct < 4; ++ct)
        bias_c[ct] = em_bias[wv*64 + ct*16 + l15];
    #pragma unroll
    for (int rt = 0; rt < 2; ++rt) {
        #pragma unroll
        for (int reg = 0; reg < 4; ++reg) {
            int r = r0 + rt*16 + q*4 + reg;
            #pragma unroll
            for (int ct = 0; ct < 4; ++ct) {
                float lv = lembs[(size_t)r*Dd + wv*64 + ct*16 + l15];
                acc[rt][ct][reg] = lv + fmaxf(acc[rt][ct][reg] + bias_c[ct], 0.f);
            }
        }
    }
    #pragma unroll
    for (int rt = 0; rt < 2; ++rt) {
        #pragma unroll
        for (int reg = 0; reg < 4; ++reg) {
            float s  = ((acc[rt][0][reg] + acc[rt][1][reg]) + (acc[rt][2][reg] + acc[rt][3][reg]));
            float ss = ((acc[rt][0][reg]*acc[rt][0][reg] + acc[rt][1][reg]*acc[rt][1][reg])
                      + (acc[rt][2][reg]*acc[rt][2][reg] + acc[rt][3][reg]*acc[rt][3][reg]));
            s  += __shfl_xor(s, 1);  ss += __shfl_xor(ss, 1);
            s  += __shfl_xor(s, 2);  ss += __shfl_xor(ss, 2);
            s  += __shfl_xor(s, 4);  ss += __shfl_xor(ss, 4);
            s  += __shfl_xor(s, 8);  ss += __shfl_xor(ss, 8);
            if (l15 == 0) {
                int rw = rt*16 + q*4 + reg;
                lsep[wv][rw][0] = s;
                lsep[wv][rw][1] = ss;
            }
        }
    }
    __syncthreads();
    if (tid < 32) {
        float s  = (lsep[0][tid][0] + lsep[1][tid][0]) + (lsep[2][tid][0] + lsep[3][tid][0]);
        float ss = (lsep[0][tid][1] + lsep[1][tid][1]) + (lsep[2][tid][1] + lsep[3][tid][1]);
        float mu = s * (1.f/Dd);
        musig[tid][0] = mu;
        musig[tid][1] = rsqrtf(ss*(1.f/Dd) - mu*mu + EPSf);
    }
    __syncthreads();
    float gl[4], bl[4];
    #pragma unroll
    for (int ct = 0; ct < 4; ++ct) {
        gl[ct] = em_g[wv*64 + ct*16 + l15];
        bl[ct] = em_beta[wv*64 + ct*16 + l15];
    }
    #pragma unroll
    for (int rt = 0; rt < 2; ++rt) {
        #pragma unroll
        for (int reg = 0; reg < 4; ++reg) {
            int rw = rt*16 + q*4 + reg;
            int r = r0 + rw;
            float mu = musig[rw][0], rs = musig[rw][1];
            unsigned short* dst = h_bf + (size_t)r*Dd + wv*64;
            #pragma unroll
            for (int ct = 0; ct < 4; ++ct)
                dst[ct*16 + l15] = f2bf((acc[rt][ct][reg] - mu)*rs*gl[ct] + bl[ct]);
        }
    }
}

// ---------------- K_emtrans: FUSED emission GEMM + transition GEMM ----------------
// bid [0,EMB):  em path (xcd-bijective remap: 4 kg-siblings of one vb share an XCD)
// bid >= EMB:   trans path, r0 = (bid-EMB)*32
union SMemU {
    struct { short hs[64][264]; } em;
    struct { short th[32][520]; float musig[32][2]; float lsep[4][32][2]; } tr;
};

__global__ __launch_bounds__(256, 4) void k_emtrans(
    const unsigned short* __restrict__ dwP, const float* __restrict__ dec_b,
    const unsigned short* __restrict__ h_bf, float* __restrict__ part,
    unsigned short* __restrict__ E2,
    const float* __restrict__ tlembs, const float* __restrict__ P0,
    const float* __restrict__ P1, const float* __restrict__ tm_bias,
    const short* __restrict__ tdwg_bf, const float* __restrict__ Gt,
    const float* __restrict__ Bt, float* __restrict__ lse_t,
    unsigned short* __restrict__ Td)
{
    __shared__ SMemU sm;
    int bid = blockIdx.x;
    int tid = threadIdx.x, lane = tid & 63, wv = tid >> 6;
    int l15 = lane & 15, q = lane >> 4;

    if (bid < EMB) {
        // ================= EM path =================
        int xcd = bid & 7, slot = bid >> 3;
        int grp = slot >> 2, kg = slot & 3;
        int vb = grp*8 + xcd;
        if (vb >= VB2) return;
        short (*hs)[264] = sm.em.hs;

        {
            int row = tid >> 2, c0 = (tid & 3) * 64;
            const short8* src = (const short8*)(h_bf + (size_t)(kg*64 + row)*Dd + c0);
            #pragma unroll
            for (int u = 0; u < 8; ++u)
                *(short8*)&hs[row][c0 + u*8] = src[u];
        }
        __syncthreads();

        f32x4 acc[4][4];
        #pragma unroll
        for (int mt = 0; mt < 4; ++mt)
            #pragma unroll
            for (int ct = 0; ct < 4; ++ct)
                acc[mt][ct] = (f32x4){0.f,0.f,0.f,0.f};

        const short8* bb8 = (const short8*)dwP + ((size_t)vb*8*16 + wv*4)*64 + lane;
        short8 Bf[3][4];
        #define LDB_EM(slot_, kk) { \
            Bf[slot_][0] = bb8[((kk)*16 + 0)*64]; \
            Bf[slot_][1] = bb8[((kk)*16 + 1)*64]; \
            Bf[slot_][2] = bb8[((kk)*16 + 2)*64]; \
            Bf[slot_][3] = bb8[((kk)*16 + 3)*64]; }
        LDB_EM(0, 0)
        LDB_EM(1, 1)
        #pragma unroll
        for (int ks = 0; ks < 8; ++ks) {
            if (ks < 6) LDB_EM((ks+2)%3, ks+2)
            short8 a[4];
            #pragma unroll
            for (int mt = 0; mt < 4; ++mt)
                a[mt] = *(const short8*)&hs[mt*16 + l15][ks*32 + q*8];
            #pragma unroll
            for (int mt = 0; mt < 4; ++mt)
                #pragma unroll
                for (int ct = 0; ct < 4; ++ct)
                    acc[mt][ct] = __builtin_amdgcn_mfma_f32_16x16x32_bf16(a[mt], Bf[ks%3][ct], acc[mt][ct], 0,0,0);
        }
        #undef LDB_EM

        int vcol[4]; bool vok[4];
        #pragma unroll
        for (int ct = 0; ct < 4; ++ct) {
            int v = vb*256 + wv*64 + l15*4 + ct;
            vok[ct] = (v < Vv);
            vcol[ct] = v < Vv ? v : Vv-1;
        }
        #pragma unroll
        for (int ct = 0; ct < 4; ++ct) {
            if (vok[ct]) {
                float db = dec_b[vcol[ct]];
                #pragma unroll
                for (int mt = 0; mt < 4; ++mt)
                    #pragma unroll
                    for (int reg = 0; reg < 4; ++reg)
                        acc[mt][ct][reg] += db;
            } else {
                #pragma unroll
                for (int mt = 0; mt < 4; ++mt)
                    #pragma unroll
                    for (int reg = 0; reg < 4; ++reg)
                        acc[mt][ct][reg] = -1e30f;
            }
        }
        #pragma unroll
        for (int mt = 0; mt < 4; ++mt) {
            #pragma unroll
            for (int reg = 0; reg < 4; ++reg) {
                int k = kg*64 + mt*16 + q*4 + reg;
                u32x2 p;
                p.x = f2bf2(acc[mt][0][reg], acc[mt][1][reg]);
                p.y = f2bf2(acc[mt][2][reg], acc[mt][3][reg]);
                *(u32x2*)(E2 + (size_t)k*VPAD + vb*256 + wv*64 + l15*4) = p;
            }
        }
        #pragma unroll
        for (int mt = 0; mt < 4; ++mt) {
            #pragma unroll
            for (int reg = 0; reg < 4; ++reg) {
                float m = fmaxf(fmaxf(acc[mt][0][reg], acc[mt][1][reg]),
                                fmaxf(acc[mt][2][reg], acc[mt][3][reg]));
                m = fmaxf(m, __shfl_xor(m, 1));
                m = fmaxf(m, __shfl_xor(m, 2));
                m = fmaxf(m, __shfl_xor(m, 4));
                m = fmaxf(m, __shfl_xor(m, 8));
                float s = __expf(acc[mt][0][reg] - m) + __expf(acc[mt][1][reg] - m)
                        + __expf(acc[mt][2][reg] - m) + __expf(acc[mt][3][reg] - m);
                s += __shfl_xor(s, 1);
                s += __shfl_xor(s, 2);
                s += __shfl_xor(s, 4);
                s += __shfl_xor(s, 8);
                if (l15 == 0) {
                    int k = kg*64 + mt*16 + q*4 + reg;
                    part[((size_t)k*VB3 + vb*4 + wv)*2]     = m;
                    part[((size_t)k*VB3 + vb*4 + wv)*2 + 1] = s;
                }
            }
        }
        return;
    }

    // ================= TRANS path =================
    short (*th)[520]   = sm.tr.th;
    float (*musig)[2]  = sm.tr.musig;
    float (*lsep)[32][2] = sm.tr.lsep;
    int r0 = (bid - EMB) * 32;

    {
        const float4* bias0 = (const float4*)tm_bias;
        const float4* bias1 = (const float4*)(tm_bias + 256);
        float4 c0 = bias0[lane], c1 = bias1[lane];
        int i0a[8], i1a[8];
        #pragma unroll
        for (int i = 0; i < 8; ++i) {
            int r = r0 + wv*8 + i; if (r >= NROWS) r = NROWS - 1;
            i0a[i] = r / KP1; i1a[i] = r - i0a[i]*KP1;
        }
        #define ROWBODY(i, A0, B0, T0, A1, B1, T1) { \
            int row = wv*8 + (i); \
            float v0 = (T0).x + fmaxf((A0).x+(B0).x+c0.x, 0.f); \
            float v1 = (T0).y + fmaxf((A0).y+(B0).y+c0.y, 0.f); \
            float v2 = (T0).z + fmaxf((A0).z+(B0).z+c0.z, 0.f); \
            float v3 = (T0).w + fmaxf((A0).w+(B0).w+c0.w, 0.f); \
            float v4 = (T1).x + fmaxf((A1).x+(B1).x+c1.x, 0.f); \
            float v5 = (T1).y + fmaxf((A1).y+(B1).y+c1.y, 0.f); \
            float v6 = (T1).z + fmaxf((A1).z+(B1).z+c1.z, 0.f); \
            float v7 = (T1).w + fmaxf((A1).w+(B1).w+c1.w, 0.f); \
            u32x2 p0; p0.x = bfpack(v0, v1); p0.y = bfpack(v2, v3); \
            u32x2 p1; p1.x = bfpack(v4, v5); p1.y = bfpack(v6, v7); \
            *(u32x2*)&th[row][lane*4]       = p0; \
            *(u32x2*)&th[row][256 + lane*4] = p1; \
            float s  = ((v0+v1)+(v2+v3)) + ((v4+v5)+(v6+v7)); \
            float ss = ((v0*v0+v1*v1)+(v2*v2+v3*v3)) + ((v4*v4+v5*v5)+(v6*v6+v7*v7)); \
            _Pragma("unroll") \
            for (int d = 1; d < 64; d <<= 1) { \
                s  += __shfl_xor(s, d); \
                ss += __shfl_xor(ss, d); \
            } \
            if (lane == 0) { \
                float mu = s * (1.f/MD); \
                musig[row][0] = mu; \
                musig[row][1] = rsqrtf(ss*(1.f/MD) - mu*mu + EPSf); \
            } }

        if (i0a[0] == i0a[7]) {
            // uniform i0 across the wave's 8 rows: hoist P0/tlembs[i0] loads
            float4 A0 = ((const float4*)(P0 + (size_t)i0a[0]*MD))[lane];
            float4 A1 = ((const float4*)(P0 + (size_t)i0a[0]*MD + 256))[lane];
            float4 T0 = ((const float4*)(tlembs + (size_t)i0a[0]*Dd))[lane];
            #pragma unroll
            for (int i = 0; i < 8; ++i) {
                float4 b0 = ((const float4*)(P1 + (size_t)i1a[i]*MD))[lane];
                float4 b1 = ((const float4*)(P1 + (size_t)i1a[i]*MD + 256))[lane];
                float4 t1 = ((const float4*)(tlembs + (size_t)i1a[i]*Dd))[lane];
                ROWBODY(i, A0, b0, T0, A1, b1, t1)
            }
        } else {
            #pragma unroll
            for (int i = 0; i < 8; ++i) {
                float4 A0 = ((const float4*)(P0 + (size_t)i0a[i]*MD))[lane];
                float4 A1 = ((const float4*)(P0 + (size_t)i0a[i]*MD + 256))[lane];
                float4 T0 = ((const float4*)(tlembs + (size_t)i0a[i]*Dd))[lane];
                float4 b0 = ((const float4*)(P1 + (size_t)i1a[i]*MD))[lane];
                float4 b1 = ((const float4*)(P1 + (size_t)i1a[i]*MD + 256))[lane];
                float4 t1 = ((const float4*)(tlembs + (size_t)i1a[i]*Dd))[lane];
                ROWBODY(i, A0, b0, T0, A1, b1, t1)
            }
        }
        #undef ROWBODY
    }
    __syncthreads();

    f32x4 acc[2][4];
    #pragma unroll
    for (int rt = 0; rt < 2; ++rt)
        #pragma unroll
        for (int ct = 0; ct < 4; ++ct)
            acc[rt][ct] = (f32x4){0.f, 0.f, 0.f, 0.f};
    const short* bb = tdwg_bf + (size_t)wv*32768 + (size_t)lane*8;
    short8 Bf[3][4];
    #define LDB_TR(slot_, kk) { const short* nxt = bb + (size_t)(kk)*2048; \
        Bf[slot_][0] = *(const short8*)(nxt); \
        Bf[slot_][1] = *(const short8*)(nxt + 512); \
        Bf[slot_][2] = *(const short8*)(nxt + 1024); \
        Bf[slot_][3] = *(const short8*)(nxt + 1536); }
    LDB_TR(0, 0)
    LDB_TR(1, 1)
    #pragma unroll
    for (int ks = 0; ks < 16; ++ks) {
        if (ks < 14) LDB_TR((ks+2)%3, ks+2)
        int ko = ks*32 + q*8;
        short8 a0 = *(const short8*)&th[ 0 + l15][ko];
        short8 a1 = *(const short8*)&th[16 + l15][ko];
        acc[0][0] = __builtin_amdgcn_mfma_f32_16x16x32_bf16(a0, Bf[ks%3][0], acc[0][0], 0,0,0);
        acc[1][0] = __builtin_amdgcn_mfma_f32_16x16x32_bf16(a1, Bf[ks%3][0], acc[1][0], 0,0,0);
        acc[0][1] = __builtin_amdgcn_mfma_f32_16x16x32_bf16(a0, Bf[ks%3][1], acc[0][1], 0,0,0);
        acc[1][1] = __builtin_amdgcn_mfma_f32_16x16x32_bf16(a1, Bf[ks%3][1], acc[1][1], 0,0,0);
        acc[0][2] = __builtin_amdgcn_mfma_f32_16x16x32_bf16(a0, Bf[ks%3][2], acc[0][2], 0,0,0);
        acc[1][2] = __builtin_amdgcn_mfma_f32_16x16x32_bf16(a1, Bf[ks%3][2], acc[1][2], 0,0,0);
        acc[0][3] = __builtin_amdgcn_mfma_f32_16x16x32_bf16(a0, Bf[ks%3][3], acc[0][3], 0,0,0);
        acc[1][3] = __builtin_amdgcn_mfma_f32_16x16x32_bf16(a1, Bf[ks%3][3], acc[1][3], 0,0,0);
    }
    #undef LDB_TR

    float4 Gc = *(const float4*)(Gt + wv*64 + l15*4);
    float4 Bc = *(const float4*)(Bt + wv*64 + l15*4);
    #pragma unroll
    for (int rt = 0; rt < 2; ++rt) {
        #pragma unroll
        for (int reg = 0; reg < 4; ++reg) {
            int rw = rt*16 + q*4 + reg;
            float mu = musig[rw][0], rs = musig[rw][1];
            float e0 = rs*(acc[rt][0][reg] - mu*Gc.x) + Bc.x;
            float e1 = rs*(acc[rt][1][reg] - mu*Gc.y) + Bc.y;
            float e2 = rs*(acc[rt][2][reg] - mu*Gc.z) + Bc.z;
            float e3 = rs*(acc[rt][3][reg] - mu*Gc.w) + Bc.w;
            long r = (long)r0 + rw;
            if (r < NROWS) {
                u32x2 p;
                p.x = f2bf2(e0, e1);
                p.y = f2bf2(e2, e3);
                *(u32x2*)(Td + (size_t)r*Kst + wv*64 + l15*4) = p;
            }
            float m = fmaxf(fmaxf(e0, e1), fmaxf(e2, e3));
            m = fmaxf(m, __shfl_xor(m, 1));
            m = fmaxf(m, __shfl_xor(m, 2));
            m = fmaxf(m, __shfl_xor(m, 4));
            m = fmaxf(m, __shfl_xor(m, 8));
            float s = __expf(e0 - m) + __expf(e1 - m) + __expf(e2 - m) + __expf(e3 - m);
            s += __shfl_xor(s, 1);
            s += __shfl_xor(s, 2);
            s += __shfl_xor(s, 4);
            s += __shfl_xor(s, 8);
            if (l15 == 0) {
                lsep[wv][rw][0] = m;
                lsep[wv][rw][1] = s;
            }
        }
    }
    __syncthreads();
    if (tid < 32) {
        int r = r0 + tid;
        if (r < NROWS) {
            float m0 = lsep[0][tid][0], m1 = lsep[1][tid][0];
            float m2 = lsep[2][tid][0], m3 = lsep[3][tid][0];
            float mg = fmaxf(fmaxf(m0, m1), fmaxf(m2, m3));
            float s = lsep[0][tid][1]*__expf(m0-mg) + lsep[1][tid][1]*__expf(m1-mg)
                    + lsep[2][tid][1]*__expf(m2-mg) + lsep[3][tid][1]*__expf(m3-mg);
            lse_t[r] = mg + logf(s);
        }
    }
}

// ---------------- K_comb: combine partials -> lse_em[k] ----------------
__global__ __launch_bounds__(64) void k_em_comb3(
    const float* __restrict__ part, float* __restrict__ lse_em)
{
    int k = blockIdx.x, lane = threadIdx.x;
    float m = -1e30f, s = 0.f;
    for (int vb = lane; vb < VB3; vb += 64) {
        float m2 = part[((size_t)k*VB3+vb)*2], s2 = part[((size_t)k*VB3+vb)*2+1];
        if (m2 > m) { s = s*__expf(m - m2) + s2; m = m2; }
        else          s += s2*__expf(m2 - m);
    }
    #pragma unroll
    for (int d = 1; d < 64; d <<= 1) {
        float mo = __shfl_xor(m, d), so = __shfl_xor(s, d);
        float mn = fmaxf(m, mo);
        s = s*__expf(m - mn) + so*__expf(mo - mn);
        m = mn;
    }
    if (lane == 0) lse_em[k] = m + logf(s);
}

// ---------------- K_gather: 2 timesteps per thread, 1 atomic ----------------
#define GT_CH 2
__global__ __launch_bounds__(256) void k_gather3(
    const int* __restrict__ x, const int* __restrict__ z,
    const unsigned short* __restrict__ E2, const float* __restrict__ lse_em,
    const unsigned short* __restrict__ Td, const float* __restrict__ lse_t,
    float* __restrict__ out)
{
    int b = threadIdx.x;
    int t0 = blockIdx.x * GT_CH;
    float accv = 0.f;
    #pragma unroll
    for (int u = 0; u < GT_CH; ++u) {
        int t = t0 + u;
        int zc = z[t*Bb + b];
        int xv = x[t*Bb + b];
        int i0 = (t >= 2) ? z[(t-2)*Bb + b] : Kst;
        int i1 = (t >= 1) ? z[(t-1)*Bb + b] : Kst;
        int lin = i0*KP1 + i1;
        accv += bf2f(E2[(size_t)zc*VPAD + xv]) - lse_em[zc]
              + bf2f(Td[(size_t)lin*Kst + zc]) - lse_t[lin];
    }
    atomicAdd(&out[b], accv);
}

extern "C" void kernel_launch(void* const* d_in, const int* in_sizes, int n_in,
                              void* d_out, int out_size, void* d_ws, size_t ws_size,
                              hipStream_t stream)
{
    const int*   x       = (const int*)  d_in[0];
    const int*   z       = (const int*)  d_in[1];
    const float* lembs   = (const float*)d_in[2];
    const float* tlembs  = (const float*)d_in[3];
    const float* dec_W   = (const float*)d_in[4];
    const float* dec_b   = (const float*)d_in[5];
    const float* em_W    = (const float*)d_in[6];
    const float* em_bias = (const float*)d_in[7];
    const float* em_g    = (const float*)d_in[8];
    const float* em_beta = (const float*)d_in[9];
    const float* td_W    = (const float*)d_in[10];
    const float* td_b    = (const float*)d_in[11];
    const float* tm_W    = (const float*)d_in[12];
    const float* tm_bias = (const float*)d_in[13];
    const float* tn_g    = (const float*)d_in[14];
    const float* tn_beta = (const float*)d_in[15];
    float* out = (float*)d_out;

    float* ws     = (float*)d_ws;
    float* P0     = ws;                    // 131584
    float* P1     = P0 + 131584;           // 131584
    float* lse_em = P1 + 131584;           // 256
    float* part   = lse_em + 256;          // 256*784*2 = 401408
    float* lse_t  = part + 401408;         // 66052
    float* Gt     = lse_t + 66052;         // 256
    float* Bt     = Gt + 256;              // 256
    unsigned short* tdwg_bf = (unsigned short*)(Bt + 256);      // 131072 ushort (fragment layout)
    unsigned short* h_bf   = tdwg_bf + 131072;                  // 65536 ushort
    unsigned short* E2     = h_bf + 65536;                      // 256*50176 ushort (25.7MB)
    unsigned short* Td     = E2 + (size_t)Kst*VPAD;             // 66049*256 ushort (33.8MB)
    unsigned short* dwP    = Td + (size_t)NROWS*Kst;            // 50176*256 ushort (25.7MB)

    hipMemsetAsync(out, 0, Bb*sizeof(float), stream);
    k_hP<<<108 + 392, 256, 0, stream>>>(lembs, em_W, em_bias, em_g, em_beta, h_bf,
                                        tlembs, tm_W, P0, P1,
                                        td_W, tn_g, tn_beta, td_b, tdwg_bf, Gt, Bt,
                                        dec_W, dwP);
    k_emtrans<<<EMB + (NROWS + 31)/32, 256, 0, stream>>>(
        dwP, dec_b, h_bf, part, E2,
        tlembs, P0, P1, tm_bias, (const short*)tdwg_bf, Gt, Bt, lse_t, Td);
    k_em_comb3<<<Kst, 64, 0, stream>>>(part, lse_em);
    k_gather3<<<Tt/GT_CH, 256, 0, stream>>>(x, z, E2, lse_em, Td, lse_t, out);
}